// Round 1
// 1166.278 us; speedup vs baseline: 1.5597x; 1.5597x over previous
//
#include <hip/hip_runtime.h>

// T=1024, B=256, I=256, H=256, fp32 in/out.
// out = outputs [T,B,H] flat, then final state [B,H].
//
// Kernel A (NEW): f16 MFMA XW = X @ W_xh + b_h. W_xh persistent in B-frags,
//   A-frags loaded directly from global (dense per-row 128B lines), grid-stride
//   over 16-row tiles. fp32 vector GEMM (~670us) -> memory-bound MFMA (~130us).
// Kernel B (NEW): raw s_barrier + counted waitcnt. Double-buffered state ->
//   1 barrier/step; vmcnt never drained so xw prefetch (distance 2, two named
//   buffers, unroll-2) and out stores stay in flight across barriers.
//   State pad 264 -> 272: reads 2-way (free), writes conflict-free.

#define TT 1024
#define BB 256
#define HH 256

typedef __attribute__((ext_vector_type(8))) _Float16 f16x8;
typedef __attribute__((ext_vector_type(4))) float f32x4;

// ---------------- Kernel A: [262144,256] @ [256,256] + bias, f16 MFMA ----------------
__global__ __launch_bounds__(256, 2) void xw_gemm_f16(const float* __restrict__ X,
                                                      const float* __restrict__ W,
                                                      const float* __restrict__ bh,
                                                      float* __restrict__ out) {
    const int tid  = threadIdx.x;
    const int lane = tid & 63;
    const int wave = tid >> 6;        // cols [wave*64, wave*64+64)
    const int c    = lane & 15;
    const int quad = lane >> 4;

    // persistent B fragments: bf[nt][kt][j] = W[(kt*32+quad*8+j)*256 + wave*64+nt*16+c]
    f16x8 bf[4][8];
#pragma unroll
    for (int nt = 0; nt < 4; nt++) {
        const int n = wave * 64 + nt * 16 + c;
#pragma unroll
        for (int kt = 0; kt < 8; kt++) {
            const int kb = kt * 32 + quad * 8;
            f16x8 v;
#pragma unroll
            for (int j = 0; j < 8; j++)
                v[j] = (_Float16)W[(size_t)(kb + j) * HH + n];
            bf[nt][kt] = v;
        }
    }
    float bb[4];
#pragma unroll
    for (int nt = 0; nt < 4; nt++) bb[nt] = bh[wave * 64 + nt * 16 + c];

    const int ntiles = (TT * BB) / 16;  // 16384 row-tiles of 16
    for (int tile = blockIdx.x; tile < ntiles; tile += gridDim.x) {
        // A fragments straight from global: row = tile*16 + c, k = kt*32 + quad*8 + j
        const float* xp = X + ((size_t)tile * 16 + c) * 256 + quad * 8;
        f16x8 af[8];
#pragma unroll
        for (int kt = 0; kt < 8; kt++) {
            float4 lo = *(const float4*)(xp + kt * 32);
            float4 hi = *(const float4*)(xp + kt * 32 + 4);
            f16x8 v;
            v[0] = (_Float16)lo.x; v[1] = (_Float16)lo.y;
            v[2] = (_Float16)lo.z; v[3] = (_Float16)lo.w;
            v[4] = (_Float16)hi.x; v[5] = (_Float16)hi.y;
            v[6] = (_Float16)hi.z; v[7] = (_Float16)hi.w;
            af[kt] = v;
        }

        f32x4 acc[4];
#pragma unroll
        for (int nt = 0; nt < 4; nt++) acc[nt] = (f32x4){0.f, 0.f, 0.f, 0.f};
#pragma unroll
        for (int kt = 0; kt < 8; kt++)
#pragma unroll
            for (int nt = 0; nt < 4; nt++)
                acc[nt] = __builtin_amdgcn_mfma_f32_16x16x32_f16(af[kt], bf[nt][kt], acc[nt], 0, 0, 0);

        // D: col = lane&15 (=c), row = quad*4 + i
        const size_t rbase = (size_t)tile * 16 + quad * 4;
#pragma unroll
        for (int nt = 0; nt < 4; nt++) {
            const int col = wave * 64 + nt * 16 + c;
#pragma unroll
            for (int i = 0; i < 4; i++)
                out[(rbase + i) * 256 + col] = acc[nt][i] + bb[nt];
        }
    }
}

// ---------------- Kernel B: MFMA recurrence ----------------
__device__ __forceinline__ float fast_tanh(float x) {
    float e = __expf(2.0f * x);
    return 1.0f - 2.0f * __builtin_amdgcn_rcpf(e + 1.0f);
}

#define SP 272  // state row pad: reads 2-way (free), writes conflict-free

// One recurrence step. CUR/NXT are compile-time 0/1. XW holds this step's xw
// values on entry and is refilled with t+2's values (consumed 2 steps later).
#define STEP(T, XW, CUR, NXT)                                                     \
    {                                                                             \
        f16x8 af[8];                                                              \
        if (realrow) {                                                            \
            _Pragma("unroll")                                                     \
            for (int kt = 0; kt < 8; kt++)                                        \
                af[kt] = *(const f16x8*)&st[CUR][r][kt * 32 + quad * 8];          \
        } else {                                                                  \
            _Pragma("unroll")                                                     \
            for (int kt = 0; kt < 8; kt++) af[kt] = (f16x8)(_Float16)0.f;         \
        }                                                                         \
        f32x4 accE[4], accO[4];                                                   \
        _Pragma("unroll")                                                         \
        for (int nt = 0; nt < 4; nt++) {                                          \
            accE[nt] = (f32x4){XW[nt], 0.f, 0.f, 0.f};                            \
            accO[nt] = (f32x4){0.f, 0.f, 0.f, 0.f};                               \
        }                                                                         \
        /* prefetch xw for T+2 (registers consumed above; loads fly over 2 steps) */ \
        {                                                                         \
            const int tp = ((T) + 2 > TT - 1) ? (TT - 1) : ((T) + 2);             \
            _Pragma("unroll")                                                     \
            for (int nt = 0; nt < 4; nt++)                                        \
                XW[nt] = out[(size_t)tp * (BB * HH) + colbase + nt * 16];         \
        }                                                                         \
        _Pragma("unroll")                                                         \
        for (int kt = 0; kt < 4; kt++)                                            \
            _Pragma("unroll")                                                     \
            for (int nt = 0; nt < 4; nt++) {                                      \
                accE[nt] = __builtin_amdgcn_mfma_f32_16x16x32_f16(af[2 * kt], bf[nt][2 * kt], accE[nt], 0, 0, 0); \
                accO[nt] = __builtin_amdgcn_mfma_f32_16x16x32_f16(af[2 * kt + 1], bf[nt][2 * kt + 1], accO[nt], 0, 0, 0); \
            }                                                                     \
        const size_t obase = (size_t)(T) * (BB * HH) + colbase;                   \
        _Pragma("unroll")                                                         \
        for (int nt = 0; nt < 4; nt++) {                                          \
            h[nt] = fast_tanh(accE[nt][0] + accO[nt][0]);                         \
            out[obase + nt * 16] = h[nt];                                         \
            st[NXT][quad][wave * 64 + nt * 16 + c] = (_Float16)h[nt];             \
        }                                                                         \
        /* reads+writes of this wave retired, then barrier; vmcnt NOT drained */  \
        asm volatile("s_waitcnt lgkmcnt(0)" ::: "memory");                        \
        __builtin_amdgcn_s_barrier();                                             \
        __builtin_amdgcn_sched_barrier(0);                                        \
    }

__global__ __launch_bounds__(256, 1) void rnn_rec_mfma(const float* __restrict__ Whh,
                                                       float* __restrict__ out) {
    // double-buffered state: step t reads st[t&1], writes st[(t+1)&1]
    __shared__ alignas(16) _Float16 st[2][4][SP];

    const int tid  = threadIdx.x;
    const int lane = tid & 63;
    const int wave = tid >> 6;        // N slice [wave*64, wave*64+64)
    const int c    = lane & 15;
    const int quad = lane >> 4;
    const int b0   = blockIdx.x * 4;  // batch rows b0..b0+3 at m = 4*r

    // persistent B fragments: bf[nt][kt][j] = W_hh[kt*32+quad*8+j][wave*64+nt*16+c]
    f16x8 bf[4][8];
#pragma unroll
    for (int nt = 0; nt < 4; nt++) {
        const int n = wave * 64 + nt * 16 + c;
#pragma unroll
        for (int kt = 0; kt < 8; kt++) {
            const int kb = kt * 32 + quad * 8;
            f16x8 v;
#pragma unroll
            for (int j = 0; j < 8; j++)
                v[j] = (_Float16)Whh[(size_t)(kb + j) * HH + n];
            bf[nt][kt] = v;
        }
    }

    // zero both state buffers
    for (int i = tid; i < 2 * 4 * SP; i += 256)
        ((_Float16*)st)[i] = (_Float16)0.f;

    const int  m       = c;               // A-row this lane serves
    const bool realrow = ((m & 3) == 0);
    const int  r       = m >> 2;          // batch row for real A lanes

    const size_t colbase = (size_t)(b0 + quad) * HH + wave * 64 + c;
    float xwA[4], xwB[4];
#pragma unroll
    for (int nt = 0; nt < 4; nt++) xwA[nt] = out[colbase + nt * 16];                    // t=0
#pragma unroll
    for (int nt = 0; nt < 4; nt++) xwB[nt] = out[(size_t)BB * HH + colbase + nt * 16];  // t=1

    asm volatile("s_waitcnt lgkmcnt(0)" ::: "memory");
    __builtin_amdgcn_s_barrier();
    __builtin_amdgcn_sched_barrier(0);

    float h[4] = {0.f, 0.f, 0.f, 0.f};

#pragma unroll 1
    for (int t = 0; t < TT; t += 2) {
        STEP(t,     xwA, 0, 1)
        STEP(t + 1, xwB, 1, 0)
    }

    const size_t fbase = (size_t)TT * (BB * HH) + colbase;
#pragma unroll
    for (int nt = 0; nt < 4; nt++) out[fbase + nt * 16] = h[nt];
}

extern "C" void kernel_launch(void* const* d_in, const int* in_sizes, int n_in,
                              void* d_out, int out_size, void* d_ws, size_t ws_size,
                              hipStream_t stream) {
    const float* X   = (const float*)d_in[0];  // [T,B,I]
    const float* Wxh = (const float*)d_in[1];  // [I,H]
    const float* Whh = (const float*)d_in[2];  // [H,H]
    const float* bh  = (const float*)d_in[3];  // [H]
    float* out = (float*)d_out;

    xw_gemm_f16<<<dim3(1024), dim3(256), 0, stream>>>(X, Wxh, bh, out);
    rnn_rec_mfma<<<dim3(BB / 4), dim3(256), 0, stream>>>(Whh, out);
}